// Round 7
// baseline (431.508 us; speedup 1.0000x reference)
//
#include <hip/hip_runtime.h>
#include <stdint.h>

#define M_DIM 8192   // BATCH*SEQ = 4*2048
#define N_DIM 4096
#define K_DIM 4096
#define BM 128
#define BN 128
#define BK 64

typedef int v4i __attribute__((ext_vector_type(4)));
typedef unsigned u32;

__device__ __forceinline__ void gll16(const void* g, void* l) {
  __builtin_amdgcn_global_load_lds(
      (const __attribute__((address_space(1))) void*)g,
      (__attribute__((address_space(3))) void*)l, 16, 0, 0);
}

__device__ __forceinline__ u32 pack4(const int4 v) {
  return (v.x & 0xffu) | ((v.y & 0xffu) << 8) | ((v.z & 0xffu) << 16) |
         ((u32)(v.w & 0xffu) << 24);
}

// ---------------------------------------------------------------------------
// prepack (fused): blocks [0,8192) pack X int32->int8; blocks [8192,12288)
// pack+transpose W int32 [K][N] -> WT int8 [N][K] via 64x64 LDS tiles.
// Inputs are int32-materialized (proven R6: detector selected int32 path).
// ---------------------------------------------------------------------------
__global__ __launch_bounds__(256) void prepack(const int4* __restrict__ Xi,
                                               u32* __restrict__ Xp,
                                               const int* __restrict__ Wi,
                                               int8_t* __restrict__ WT) {
  __shared__ u32 lds[64 * 21];
  const int tid = threadIdx.x;
  if (blockIdx.x < 8192) {
    const int base = blockIdx.x * 1024 + tid;
#pragma unroll
    for (int j = 0; j < 4; ++j) {
      const int idx = base + j * 256;
      Xp[idx] = pack4(Xi[idx]);
    }
    return;
  }
  const int bid = blockIdx.x - 8192;
  const int tk = bid & 63;   // k-tile (K/64)
  const int tn = bid >> 6;   // n-tile
  const int k0 = tk * 64, n0 = tn * 64;
#pragma unroll
  for (int j = 0; j < 4; ++j) {
    const int id = j * 256 + tid;
    const int k = id >> 4, c = id & 15;
    const int4 v = *(const int4*)(Wi + (size_t)(k0 + k) * N_DIM + n0 + c * 4);
    lds[k * 21 + c] = pack4(v);
  }
  __syncthreads();
  const int kd = tid & 15, nq = tid >> 4;
  const u32 d0 = lds[(kd * 4 + 0) * 21 + nq];
  const u32 d1 = lds[(kd * 4 + 1) * 21 + nq];
  const u32 d2 = lds[(kd * 4 + 2) * 21 + nq];
  const u32 d3 = lds[(kd * 4 + 3) * 21 + nq];
  u32* outp = (u32*)WT;
#pragma unroll
  for (int i = 0; i < 4; ++i) {
    const u32 e = ((d0 >> (8 * i)) & 0xffu) | (((d1 >> (8 * i)) & 0xffu) << 8) |
                  (((d2 >> (8 * i)) & 0xffu) << 16) |
                  (((d3 >> (8 * i)) & 0xffu) << 24);
    const int n = n0 + nq * 4 + i;
    outp[(size_t)n * (K_DIM / 4) + (k0 / 4) + kd] = e;
  }
}

// ---------------------------------------------------------------------------
// GEMM, m97 structure + XOR-swizzled LDS layout.
//
// Staging (HW-fixed LDS side: dest = base + lane*16): LDS slot s=tid&7 within
// 128-B row-pair blk=tid>>3 holds global (row 2*blk+p, k-chunk q) where
// (q + 4p) = s ^ (blk&3). Fragment read for row l16(+16i), chunk quad lands at
// slot (quad + 4*(l16&1)) ^ ((l16>>1)&3): every consecutive-8-lane group hits
// all 8 distinct 16-B bank positions -> conflict-free ds_read_b128.
// ---------------------------------------------------------------------------
__global__ __launch_bounds__(256) void gemm_packed(
    const int8_t* __restrict__ X, const int8_t* __restrict__ WT,
    const float* __restrict__ aScale, const float* __restrict__ bScale,
    int* __restrict__ Y) {
  __shared__ __align__(16) int8_t As[BM * BK];  // 8 KB
  __shared__ __align__(16) int8_t Bs[BN * BK];  // 8 KB
  const int tid = threadIdx.x;
  const int lane = tid & 63, wave = tid >> 6;
  const int quad = lane >> 4, l16 = lane & 15;
  const int wm = wave & 1, wn = wave >> 1;
  const int bn = blockIdx.x & 31;   // N/BN = 32 (bn-fast: L2 sharing)
  const int bm = blockIdx.x >> 5;   // M/BM = 64

  // swizzled staging source map
  const int s = tid & 7, blk = tid >> 3;
  const int t = s ^ (blk & 3);
  const int q = t & 3, p = t >> 2;
  const int row = 2 * blk + p;  // 0..63
  const int8_t* Ag0 = X + (size_t)(bm * BM + row) * K_DIM + q * 16;
  const int8_t* Ag1 = Ag0 + (size_t)64 * K_DIM;
  const int8_t* Bg0 = WT + (size_t)(bn * BN + row) * K_DIM + q * 16;
  const int8_t* Bg1 = Bg0 + (size_t)64 * K_DIM;
  int8_t* Al0 = As + tid * 16;
  int8_t* Al1 = Al0 + 4096;
  int8_t* Bl0 = Bs + tid * 16;
  int8_t* Bl1 = Bl0 + 4096;

  v4i acc[4][4] = {};

  // swizzled fragment read base (fragment i at +i*1024)
  const int slot = (quad + 4 * (l16 & 1)) ^ ((l16 >> 1) & 3);
  const int8_t* aLds = As + (wm * 32 + (l16 >> 1)) * 128 + slot * 16;
  const int8_t* bLds = Bs + (wn * 32 + (l16 >> 1)) * 128 + slot * 16;

  for (int k0 = 0; k0 < K_DIM; k0 += BK) {
    gll16(Ag0 + k0, Al0);
    gll16(Ag1 + k0, Al1);
    gll16(Bg0 + k0, Bl0);
    gll16(Bg1 + k0, Bl1);
    __syncthreads();
    v4i af[4], bf[4];
#pragma unroll
    for (int i = 0; i < 4; ++i) af[i] = *(const v4i*)(aLds + i * 1024);
#pragma unroll
    for (int i = 0; i < 4; ++i) bf[i] = *(const v4i*)(bLds + i * 1024);
#pragma unroll
    for (int mi = 0; mi < 4; ++mi)
#pragma unroll
      for (int ni = 0; ni < 4; ++ni)
        acc[mi][ni] = __builtin_amdgcn_mfma_i32_16x16x64_i8(
            af[mi], bf[ni], acc[mi][ni], 0, 0, 0);
    __syncthreads();
  }

  // epilogue: C/D layout col = lane&15, row = quad*4 + reg.
  // ((acc*a)*b) matches numpy's left-assoc fp32; rintf = round-half-even.
  const float a = aScale[0];
  const int nBase = bn * BN + wn * 64 + l16;
  float bs[4];
#pragma unroll
  for (int ni = 0; ni < 4; ++ni) bs[ni] = bScale[nBase + ni * 16];
#pragma unroll
  for (int mi = 0; mi < 4; ++mi) {
    const int m0 = bm * BM + wm * 64 + mi * 16 + quad * 4;
#pragma unroll
    for (int r = 0; r < 4; ++r) {
      int* rowp = Y + (size_t)(m0 + r) * N_DIM + nBase;
#pragma unroll
      for (int ni = 0; ni < 4; ++ni) {
        float v = ((float)acc[mi][ni][r] * a) * bs[ni];
        v = rintf(v);
        v = fminf(fmaxf(v, -128.f), 127.f);
        rowp[ni * 16] = (int)v;
      }
    }
  }
}

extern "C" void kernel_launch(void* const* d_in, const int* in_sizes, int n_in,
                              void* d_out, int out_size, void* d_ws,
                              size_t ws_size, hipStream_t stream) {
  const int4* Xi = (const int4*)d_in[0];  // [8192][4096] int8 vals as int32
  const int* Wi = (const int*)d_in[1];    // [4096][4096] as int32, [K][N]
  const float* a = (const float*)d_in[2];
  const float* b = (const float*)d_in[3];
  int* Y = (int*)d_out;                   // [8192][4096] int32

  const size_t xB = (size_t)M_DIM * K_DIM;  // 32 MB packed X
  int8_t* Xp = (int8_t*)d_ws;
  int8_t* WT = (int8_t*)d_ws + xB;          // 16 MB packed W^T
  // ws_size >= 48 MB proven in R6 (gemm_packed branch ran and passed).

  prepack<<<8192 + (K_DIM / 64) * (N_DIM / 64), 256, 0, stream>>>(
      Xi, (u32*)Xp, Wi, WT);
  gemm_packed<<<(M_DIM / BM) * (N_DIM / BN), 256, 0, stream>>>(Xp, WT, a, b, Y);
}